// Round 1
// baseline (1661.430 us; speedup 1.0000x reference)
//
#include <hip/hip_runtime.h>

#define D 128
#define TRK 128
#define NB 64
#define LBUF 96
#define T_STEPS 189
#define NWG 32
#define NTHR 256
#define SLOTS 98

typedef __bf16 bf16x8 __attribute__((ext_vector_type(8)));
typedef float f32x4 __attribute__((ext_vector_type(4)));

__device__ __forceinline__ unsigned short f2bf(float f){
  unsigned x = __builtin_bit_cast(unsigned, f);
  unsigned r = (x + 0x7fffu + ((x >> 16) & 1u)) >> 16;
  return (unsigned short)r;
}
__device__ __forceinline__ float bf2f(unsigned short u){
  unsigned x = ((unsigned)u) << 16;
  return __builtin_bit_cast(float, x);
}
__device__ __forceinline__ float sigf(float x){ return 1.f / (1.f + __expf(-x)); }
__device__ __forceinline__ float tanhfast(float x){ return 1.f - 2.f / (__expf(2.f * x) + 1.f); }

// ws layout (bytes)
#define WS_BUFH   0u          // ushort[96*64*128]   bf16 h-halves of buffers
#define WS_STACKH 1572864u    // ushort[64*98*128]   stack h (bf16)
#define WS_STACKC 3178496u    // float [64*98*128]   stack c (fp32)
#define WS_TH     6389760u    // ushort[2*64*128]    tracker h double buffer (bf16)
#define WS_BAR    6422528u    // unsigned counter

// monotonic-counter grid barrier (agent scope: release on arrive, acquire on spin)
__device__ __forceinline__ void gbar(unsigned* cnt, unsigned target){
  __syncthreads();
  if (threadIdx.x == 0){
    __hip_atomic_fetch_add(cnt, 1u, __ATOMIC_RELEASE, __HIP_MEMORY_SCOPE_AGENT);
    while (__hip_atomic_load(cnt, __ATOMIC_ACQUIRE, __HIP_MEMORY_SCOPE_AGENT) < target)
      __builtin_amdgcn_s_sleep(1);
  }
  __syncthreads();
}

__global__ __launch_bounds__(NTHR, 1) void spinn_kernel(
    const float* __restrict__ buffers, const int* __restrict__ trans,
    const float* __restrict__ W_ih, const float* __restrict__ W_hh,
    const float* __restrict__ b_ih, const float* __restrict__ b_hh,
    const float* __restrict__ Wl, const float* __restrict__ bl,
    const float* __restrict__ Wr, const float* __restrict__ Wt,
    float* __restrict__ out, unsigned char* __restrict__ ws)
{
  unsigned short* bufh   = (unsigned short*)(ws + WS_BUFH);
  unsigned short* stackh = (unsigned short*)(ws + WS_STACKH);
  float*          stackc = (float*)(ws + WS_STACKC);
  unsigned short* thbuf  = (unsigned short*)(ws + WS_TH);
  unsigned*       barcnt = (unsigned*)(ws + WS_BAR);

  // WA: [src(4)][kb(4)][lane(64)][j(8)]  B-fragments for gates (srcs: buf,s1,s2,th)
  // WB: [src(3)*2+tile][kb(4)][lane(64)][j(8)] B-fragments for composition (srcs: s2->Wl, s1->Wr, th2->Wt)
  __shared__ alignas(16) unsigned short WA_lds[4 * 4 * 64 * 8];
  __shared__ alignas(16) unsigned short WB_lds[6 * 4 * 64 * 8];
  __shared__ float stage[4][16][32];
  __shared__ float tc_lds[256];     // [row(64)][dl(4)]
  __shared__ float biasA[16];
  __shared__ float biasB[20];
  __shared__ int tr_lds[64];
  __shared__ int sp_lds[64];
  __shared__ int bp_lds[64];

  const int tid  = threadIdx.x;
  const int blk  = blockIdx.x;
  const int lane = tid & 63;
  const int w    = tid >> 6;
  const int gid  = blk * NTHR + tid;

  // ---- init: weight slices into LDS (fp32 -> bf16) ----
  for (int idx = tid; idx < 4 * 4 * 64 * 8; idx += NTHR){
    int j = idx & 7, ln = (idx >> 3) & 63, kb = (idx >> 9) & 3, src = idx >> 11;
    int v = ln & 15;
    int col = (v >> 2) * 128 + 4 * blk + (v & 3);      // quad(i,f,g,o)*128 + dim
    int k = kb * 32 + (ln >> 4) * 8 + j;
    float val = (src < 3) ? W_ih[col * 384 + src * 128 + k] : W_hh[col * 128 + k];
    WA_lds[idx] = f2bf(val);
  }
  for (int idx = tid; idx < 6 * 4 * 64 * 8; idx += NTHR){
    int j = idx & 7, ln = (idx >> 3) & 63, kb = (idx >> 9) & 3, Tt = (idx >> 11) & 1, src = idx >> 12;
    int v = ln & 15;
    int k = kb * 32 + (ln >> 4) * 8 + j;
    float val = 0.f;
    if (Tt == 0){
      int col = (v >> 2) * 128 + 4 * blk + (v & 3);    // quads g,i,f1,f2
      const float* Wm = (src == 0) ? Wl : ((src == 1) ? Wr : Wt);
      val = Wm[col * 128 + k];
    } else if ((v >> 2) == 0){
      int col = 512 + 4 * blk + (v & 3);               // o quad; rest padded 0
      const float* Wm = (src == 0) ? Wl : ((src == 1) ? Wr : Wt);
      val = Wm[col * 128 + k];
    }
    WB_lds[idx] = f2bf(val);
  }
  if (tid < 16){ int col = (tid >> 2) * 128 + 4 * blk + (tid & 3); biasA[tid] = b_ih[col] + b_hh[col]; }
  if (tid < 20){
    int col = (tid < 16) ? ((tid >> 2) * 128 + 4 * blk + (tid & 3)) : (512 + 4 * blk + (tid - 16));
    biasB[tid] = bl[col];
  }
  tc_lds[tid] = 0.f;
  if (tid < 64){ sp_lds[tid] = 2; bp_lds[tid] = LBUF; }

  // ---- init: global tables ----
  for (int i = gid; i < LBUF * NB * D; i += NWG * NTHR){
    int k = i & 127; int rb = i >> 7;                  // rb = lrow*64 + b
    bufh[i] = f2bf(buffers[rb * 256 + k]);
  }
  for (int i = gid; i < NB * D; i += NWG * NTHR){
    int b = i >> 7, k = i & 127;
    unsigned short h = f2bf(buffers[b * 256 + k]);
    float c = buffers[b * 256 + 128 + k];
    stackh[(b * SLOTS + 0) * 128 + k] = h;
    stackh[(b * SLOTS + 1) * 128 + k] = h;
    stackc[(b * SLOTS + 0) * 128 + k] = c;
    stackc[(b * SLOTS + 1) * 128 + k] = c;
  }
  for (int i = gid; i < 2 * NB * TRK; i += NWG * NTHR) thbuf[i] = 0;

  unsigned barn = 0;
  gbar(barcnt, ++barn * NWG);

  const bf16x8* WAf = (const bf16x8*)WA_lds;
  const bf16x8* WBf = (const bf16x8*)WB_lds;
  const int r    = w * 16 + (lane & 15);   // batch row this lane owns (A-frag & elementwise)
  const int koff = (lane >> 4) * 8;        // k offset within 32-wide k-block
  const int dl   = lane >> 4;              // local dim 0..3
  const int dim  = 4 * blk + dl;           // owned tracker/comp dim

  for (int t = 0; t < T_STEPS; ++t){
    if (tid < 64) tr_lds[tid] = trans[t * 64 + tid];
    __syncthreads();
    const int anyRed = __syncthreads_or((tid < 64) && (tr_lds[tid] == 2));
    const unsigned short* th_rd = thbuf + (t & 1) * NB * TRK;
    unsigned short*       th_wr = thbuf + ((t + 1) & 1) * NB * TRK;

    // ================= phase A: tracker gates =================
    {
      int sp_r = sp_lds[r], bp_r = bp_lds[r];
      const unsigned short* pb = bufh   + ((bp_r - 1) * 64 + r) * 128 + koff;
      const unsigned short* p1 = stackh + (r * SLOTS + sp_r - 1) * 128 + koff;
      const unsigned short* p2 = stackh + (r * SLOTS + sp_r - 2) * 128 + koff;
      const unsigned short* pt = th_rd  + r * 128 + koff;
      bf16x8 a0[4], a1[4], a2[4], a3[4];
      #pragma unroll
      for (int kb = 0; kb < 4; kb++){
        a0[kb] = *(const bf16x8*)(pb + kb * 32);
        a1[kb] = *(const bf16x8*)(p1 + kb * 32);
        a2[kb] = *(const bf16x8*)(p2 + kb * 32);
        a3[kb] = *(const bf16x8*)(pt + kb * 32);
      }
      f32x4 acc = {0.f, 0.f, 0.f, 0.f};
      #pragma unroll
      for (int kb = 0; kb < 4; kb++) acc = __builtin_amdgcn_mfma_f32_16x16x32_bf16(a0[kb], WAf[(0 * 4 + kb) * 64 + lane], acc, 0, 0, 0);
      #pragma unroll
      for (int kb = 0; kb < 4; kb++) acc = __builtin_amdgcn_mfma_f32_16x16x32_bf16(a1[kb], WAf[(1 * 4 + kb) * 64 + lane], acc, 0, 0, 0);
      #pragma unroll
      for (int kb = 0; kb < 4; kb++) acc = __builtin_amdgcn_mfma_f32_16x16x32_bf16(a2[kb], WAf[(2 * 4 + kb) * 64 + lane], acc, 0, 0, 0);
      #pragma unroll
      for (int kb = 0; kb < 4; kb++) acc = __builtin_amdgcn_mfma_f32_16x16x32_bf16(a3[kb], WAf[(3 * 4 + kb) * 64 + lane], acc, 0, 0, 0);
      #pragma unroll
      for (int j = 0; j < 4; j++) stage[w][(lane >> 4) * 4 + j][lane & 15] = acc[j];
    }
    __syncthreads();
    {
      int r16 = lane & 15;
      float iv = stage[w][r16][0 + dl]  + biasA[0 + dl];
      float fv = stage[w][r16][4 + dl]  + biasA[4 + dl];
      float gv = stage[w][r16][8 + dl]  + biasA[8 + dl];
      float ov = stage[w][r16][12 + dl] + biasA[12 + dl];
      float tco = tc_lds[r * 4 + dl];
      float tc2 = sigf(fv) * tco + sigf(iv) * tanhfast(gv);
      float th2 = sigf(ov) * tanhfast(tc2);
      tc_lds[r * 4 + dl] = tc2;
      th_wr[r * 128 + dim] = f2bf(th2);
      // shift push: stack[sp] = buf_top (our 4 dims of h and c)
      if (tr_lds[r] == 3){
        int slot = sp_lds[r]; int bp_r = bp_lds[r];
        stackh[(r * SLOTS + slot) * 128 + dim] = bufh[((bp_r - 1) * 64 + r) * 128 + dim];
        stackc[(r * SLOTS + slot) * 128 + dim] = buffers[((bp_r - 1) * 64 + r) * 256 + 128 + dim];
      }
    }
    gbar(barcnt, ++barn * NWG);

    // ================= phase B: composition (reduce steps) =================
    if (anyRed){
      {
        int sp_r = sp_lds[r];
        const unsigned short* p2 = stackh + (r * SLOTS + sp_r - 2) * 128 + koff;
        const unsigned short* p1 = stackh + (r * SLOTS + sp_r - 1) * 128 + koff;
        const unsigned short* pt = th_wr + r * 128 + koff;
        bf16x8 a0[4], a1[4], a2[4];
        #pragma unroll
        for (int kb = 0; kb < 4; kb++){
          a0[kb] = *(const bf16x8*)(p2 + kb * 32);   // s2 -> Wl
          a1[kb] = *(const bf16x8*)(p1 + kb * 32);   // s1 -> Wr
          a2[kb] = *(const bf16x8*)(pt + kb * 32);   // th2 -> Wt
        }
        f32x4 acc0 = {0.f, 0.f, 0.f, 0.f}, acc1 = {0.f, 0.f, 0.f, 0.f};
        #pragma unroll
        for (int kb = 0; kb < 4; kb++){
          acc0 = __builtin_amdgcn_mfma_f32_16x16x32_bf16(a0[kb], WBf[(0 * 4 + kb) * 64 + lane], acc0, 0, 0, 0);
          acc1 = __builtin_amdgcn_mfma_f32_16x16x32_bf16(a0[kb], WBf[(1 * 4 + kb) * 64 + lane], acc1, 0, 0, 0);
          acc0 = __builtin_amdgcn_mfma_f32_16x16x32_bf16(a1[kb], WBf[(2 * 4 + kb) * 64 + lane], acc0, 0, 0, 0);
          acc1 = __builtin_amdgcn_mfma_f32_16x16x32_bf16(a1[kb], WBf[(3 * 4 + kb) * 64 + lane], acc1, 0, 0, 0);
          acc0 = __builtin_amdgcn_mfma_f32_16x16x32_bf16(a2[kb], WBf[(4 * 4 + kb) * 64 + lane], acc0, 0, 0, 0);
          acc1 = __builtin_amdgcn_mfma_f32_16x16x32_bf16(a2[kb], WBf[(5 * 4 + kb) * 64 + lane], acc1, 0, 0, 0);
        }
        #pragma unroll
        for (int j = 0; j < 4; j++){
          stage[w][(lane >> 4) * 4 + j][lane & 15]      = acc0[j];
          stage[w][(lane >> 4) * 4 + j][16 + (lane & 15)] = acc1[j];
        }
      }
      __syncthreads();
      {
        int r16 = lane & 15;
        int sp_r = sp_lds[r];
        float gv  = stage[w][r16][0 + dl]  + biasB[0 + dl];
        float iv  = stage[w][r16][4 + dl]  + biasB[4 + dl];
        float f1v = stage[w][r16][8 + dl]  + biasB[8 + dl];
        float f2v = stage[w][r16][12 + dl] + biasB[12 + dl];
        float ov  = stage[w][r16][16 + dl] + biasB[16 + dl];
        float s2c = stackc[(r * SLOTS + sp_r - 2) * 128 + dim];
        float s1c = stackc[(r * SLOTS + sp_r - 1) * 128 + dim];
        float c = sigf(f1v) * s2c + sigf(f2v) * s1c + sigf(iv) * tanhfast(gv);
        float h = sigf(ov) * tanhfast(c);
        if (tr_lds[r] == 2){
          stackh[(r * SLOTS + sp_r - 2) * 128 + dim] = f2bf(h);
          stackc[(r * SLOTS + sp_r - 2) * 128 + dim] = c;
        }
      }
      gbar(barcnt, ++barn * NWG);
    }

    // sp/bp update (uniform per row; LDS-local, resynced at top of next iter)
    if (tid < 64){
      int tr = tr_lds[tid];
      sp_lds[tid] += (tr == 3) - (tr == 2);
      bp_lds[tid] -= (tr == 3);
    }
    __syncthreads();
  }

  // ---- epilogue: out[b, :] = h of stack top (each WG writes its 4 dims) ----
  {
    int rr = tid & 63, dle = tid >> 6;
    int dme = 4 * blk + dle;
    out[rr * 128 + dme] = bf2f(stackh[(rr * SLOTS + sp_lds[rr] - 1) * 128 + dme]);
  }
}

extern "C" void kernel_launch(void* const* d_in, const int* in_sizes, int n_in,
                              void* d_out, int out_size, void* d_ws, size_t ws_size,
                              hipStream_t stream){
  const float* buffers = (const float*)d_in[0];
  const int*   trans   = (const int*)d_in[1];
  const float* W_ih    = (const float*)d_in[2];
  const float* W_hh    = (const float*)d_in[3];
  const float* b_ih    = (const float*)d_in[4];
  const float* b_hh    = (const float*)d_in[5];
  const float* Wl      = (const float*)d_in[6];
  const float* bl      = (const float*)d_in[7];
  const float* Wr      = (const float*)d_in[8];
  const float* Wt      = (const float*)d_in[9];
  unsigned char* ws = (unsigned char*)d_ws;
  hipMemsetAsync(ws + WS_BAR, 0, 128, stream);  // reset barrier counter (in-graph)
  spinn_kernel<<<dim3(NWG), dim3(NTHR), 0, stream>>>(
      buffers, trans, W_ih, W_hh, b_ih, b_hh, Wl, bl, Wr, Wt,
      (float*)d_out, ws);
}